// Round 15
// baseline (310.877 us; speedup 1.0000x reference)
//
#include <hip/hip_runtime.h>
#include <math.h>

// B=16, L=64, H=512, N_LABELS=64, ITERS=3
//
// ws layout (float offsets):
//   wbp 0 [131072] W_ID bf16 B-fragment-major
//   v1h 393216, v1l 524288 [131072 each] split-bf16 V1
//   sfbuf 655360, r_slot 1179648, hid 1703936 [524288 each]
//   smat 2228224 [4096], f 2232320 [8192]
//   wia_t 2240512, wsa_t 2306048 [65536 each]
//   wsf_t 2371584, vsf_t 2633728 [262144 each]

typedef __attribute__((ext_vector_type(8))) short bf16x8;
typedef __attribute__((ext_vector_type(4))) float f32x4;

__device__ inline short f2bf(float x) {  // RNE
  unsigned u = __float_as_uint(x);
  unsigned r = (u + 0x7fffu + ((u >> 16) & 1u)) >> 16;
  return (short)r;
}
__device__ inline float bf2f(short s) {
  return __uint_as_float(((unsigned)(unsigned short)s) << 16);
}
__device__ inline unsigned pack2(float a, float b) {  // truncating 2xbf16
  return (__float_as_uint(a) >> 16) | (__float_as_uint(b) & 0xffff0000u);
}
__device__ inline float ftanh(float x) {
  float t = __expf(2.f * x);
  return 1.f - 2.f * __builtin_amdgcn_rcpf(t + 1.f);
}
__device__ inline void split8(float4 a, float4 b, bf16x8* hi, bf16x8* lo) {
  float xs[8] = {a.x, a.y, a.z, a.w, b.x, b.y, b.z, b.w};
  bf16x8 h, l;
#pragma unroll
  for (int e = 0; e < 8; ++e) {
    short hh = f2bf(xs[e]);
    h[e] = hh;
    l[e] = f2bf(xs[e] - bf2f(hh));
  }
  *hi = h;
  *lo = l;
}

// ---- first linear (raw f32 B, split in-register) + all prep as extra planes.
__global__ __launch_bounds__(256) void k_lin1(
    const float* __restrict__ A, const float* __restrict__ rawB,
    const float* __restrict__ bias, float* __restrict__ C,
    const float* __restrict__ W_ID, const float* __restrict__ V1,
    const float* __restrict__ W_ia, const float* __restrict__ W_sa,
    const float* __restrict__ W_SF, const float* __restrict__ V_SF,
    short* __restrict__ wbp, short* __restrict__ v1h, short* __restrict__ v1l,
    float* __restrict__ wia_t, float* __restrict__ wsa_t,
    float* __restrict__ wsf_t, float* __restrict__ vsf_t,
    float* __restrict__ fzero) {
  __shared__ short Ah[2][512], Al[2][512];
  __shared__ float tile[64][65];
  const int nh = blockIdx.y;
  const int t = threadIdx.x;

  if (nh >= 4) {
    const int pid = (nh - 4) * 64 + blockIdx.x;
    if (pid < 256) {  // wbp pack
#pragma unroll
      for (int e = 0; e < 4; ++e) {
        int idx = pid * 1024 + e * 256 + t;
        int j = idx & 7, lane = (idx >> 3) & 63;
        int ntile = (idx >> 9) & 31, kstep = idx >> 14;
        int g = ntile * 16 + (lane & 15);
        int h = kstep * 32 + (lane >> 4) * 8 + j;
        wbp[idx] = f2bf(W_ID[g * 512 + h]);
      }
    } else if (pid < 512) {  // v1 split pack
      int p = pid - 256;
#pragma unroll
      for (int e = 0; e < 4; ++e) {
        int idx = p * 1024 + e * 256 + t;
        int j = idx & 7, lane = (idx >> 3) & 63;
        int ntile = (idx >> 9) & 31, kstep = idx >> 14;
        int g = ntile * 16 + (lane & 15);
        int h = kstep * 32 + (lane >> 4) * 8 + j;
        float x = V1[g * 512 + h];
        short hi = f2bf(x);
        v1h[idx] = hi;
        v1l[idx] = f2bf(x - bf2f(hi));
      }
    } else if (pid < 672) {  // transposes
      int p = pid - 512;
      const float* tin;
      float* tout;
      int R, C2, c0, r0;
      if (p < 64) {
        tin = W_SF; tout = wsf_t; R = 512; C2 = 512;
        c0 = (p & 7) * 64; r0 = (p >> 3) * 64;
      } else if (p < 128) {
        int q = p - 64;
        tin = V_SF; tout = vsf_t; R = 512; C2 = 512;
        c0 = (q & 7) * 64; r0 = (q >> 3) * 64;
      } else if (p < 144) {
        tin = W_ia; tout = wia_t; R = 64; C2 = 1024;
        c0 = (p - 128) * 64; r0 = 0;
      } else {
        tin = W_sa; tout = wsa_t; R = 64; C2 = 1024;
        c0 = (p - 144) * 64; r0 = 0;
      }
      const int tx = t & 63, ty = t >> 6;
#pragma unroll
      for (int it2 = 0; it2 < 16; ++it2) {
        int rl = ty + it2 * 4;
        tile[rl][tx] = tin[(r0 + rl) * C2 + c0 + tx];
      }
      __syncthreads();
#pragma unroll
      for (int it2 = 0; it2 < 16; ++it2) {
        int cl = ty + it2 * 4;
        tout[(c0 + cl) * R + r0 + tx] = tile[tx][cl];
      }
    }
    return;
  }

  // ---- gemm planes (nh<4): raw f32 B, split in-register ----
  const int m0 = blockIdx.x * 16;
  if (fzero && nh == 1 && blockIdx.x < 16) {
    fzero[blockIdx.x * 512 + t] = 0.f;
    fzero[blockIdx.x * 512 + 256 + t] = 0.f;
  }
  const int w = t >> 6, lane = t & 63;
  const int lq = lane >> 4, lm = lane & 15;
  f32x4 acc[2];
#pragma unroll
  for (int c = 0; c < 2; ++c) acc[c] = (f32x4){0.f, 0.f, 0.f, 0.f};

  const int nt0 = nh * 8 + w * 2;
  const float* vb0 = rawB + (nt0 * 16 + lm) * 512 + lq * 8;
  const float* vb1 = vb0 + 16 * 512;

  const int la = t >> 2, j0 = (t & 3) * 2;
  const int m = la & 15, kk = (la >> 4) * 8 + j0;
  const float* abase = A + (m0 + m) * 512 + kk;
  float2 x = *(const float2*)abase;

  for (int ks = 0; ks < 16; ++ks) {
    const int buf = ks & 1;
    float4 q0 = *(const float4*)(vb0 + ks * 32);
    float4 q1 = *(const float4*)(vb0 + ks * 32 + 4);
    float4 p0 = *(const float4*)(vb1 + ks * 32);
    float4 p1 = *(const float4*)(vb1 + ks * 32 + 4);
    float2 xn = x;
    if (ks < 15) xn = *(const float2*)(abase + (ks + 1) * 32);
    short h0 = f2bf(x.x), h1 = f2bf(x.y);
    short l0 = f2bf(x.x - bf2f(h0)), l1 = f2bf(x.y - bf2f(h1));
    *(short2*)&Ah[buf][t * 2] = make_short2(h0, h1);
    *(short2*)&Al[buf][t * 2] = make_short2(l0, l1);
    bf16x8 b0h, b0l, b1h, b1l;
    split8(q0, q1, &b0h, &b0l);
    split8(p0, p1, &b1h, &b1l);
    __syncthreads();
    bf16x8 ah = *(const bf16x8*)&Ah[buf][lane * 8];
    bf16x8 al = *(const bf16x8*)&Al[buf][lane * 8];
    acc[0] = __builtin_amdgcn_mfma_f32_16x16x32_bf16(ah, b0h, acc[0], 0, 0, 0);
    acc[0] = __builtin_amdgcn_mfma_f32_16x16x32_bf16(al, b0h, acc[0], 0, 0, 0);
    acc[0] = __builtin_amdgcn_mfma_f32_16x16x32_bf16(ah, b0l, acc[0], 0, 0, 0);
    acc[1] = __builtin_amdgcn_mfma_f32_16x16x32_bf16(ah, b1h, acc[1], 0, 0, 0);
    acc[1] = __builtin_amdgcn_mfma_f32_16x16x32_bf16(al, b1h, acc[1], 0, 0, 0);
    acc[1] = __builtin_amdgcn_mfma_f32_16x16x32_bf16(ah, b1l, acc[1], 0, 0, 0);
    x = xn;
  }
#pragma unroll
  for (int c = 0; c < 2; ++c)
#pragma unroll
    for (int reg = 0; reg < 4; ++reg) {
      int mm = m0 + lq * 4 + reg;
      int n = (nt0 + c) * 16 + lm;
      C[mm * 512 + n] = acc[c][reg] + bias[n];
    }
}

// ---- split-precision MFMA linear (loop version, packed B), round-13 config.
// grid (64, 4); A = f[b,:] (x) c_slot, nh==0 writes r_slot, zeroes smat.
__global__ __launch_bounds__(256) void k_lin(const float* __restrict__ c_slot,
                                             const float* __restrict__ f,
                                             const short* __restrict__ bh,
                                             const short* __restrict__ bl,
                                             float* __restrict__ C,
                                             float* __restrict__ rs_out,
                                             float* __restrict__ smat0) {
  __shared__ short Ah[2][512], Al[2][512];
  __shared__ float fl[512];
  const int m0 = blockIdx.x * 16;
  const int nh = blockIdx.y;
  const int t = threadIdx.x;
  if (nh == 0 && blockIdx.x < 8) {
    smat0[blockIdx.x * 512 + t] = 0.f;
    smat0[blockIdx.x * 512 + 256 + t] = 0.f;
  }
  fl[t] = f[(blockIdx.x >> 2) * 512 + t];
  fl[t + 256] = f[(blockIdx.x >> 2) * 512 + 256 + t];
  const int w = t >> 6, lane = t & 63;
  const int lq = lane >> 4, lm = lane & 15;
  f32x4 acc[2];
#pragma unroll
  for (int c = 0; c < 2; ++c) acc[c] = (f32x4){0.f, 0.f, 0.f, 0.f};

  const bf16x8* gbh = (const bf16x8*)bh + (nh * 8 + w * 2) * 64 + lane;
  const bf16x8* gbl = (const bf16x8*)bl + (nh * 8 + w * 2) * 64 + lane;

  const int la = t >> 2, j0 = (t & 3) * 2;
  const int m = la & 15, kk = (la >> 4) * 8 + j0;
  const float* abase = c_slot + (m0 + m) * 512 + kk;
  float* rbase = rs_out + (m0 + m) * 512 + kk;
  __syncthreads();  // fl ready
  float2 x = *(const float2*)abase;

  for (int ks = 0; ks < 16; ++ks) {
    const int buf = ks & 1;
    bf16x8 b0h = gbh[ks * 2048];
    bf16x8 b1h = gbh[ks * 2048 + 64];
    bf16x8 b0l = gbl[ks * 2048];
    bf16x8 b1l = gbl[ks * 2048 + 64];
    float2 xn = x;
    if (ks < 15) xn = *(const float2*)(abase + (ks + 1) * 32);
    float a0 = x.x * fl[ks * 32 + kk];
    float a1 = x.y * fl[ks * 32 + kk + 1];
    if (nh == 0) *(float2*)(rbase + ks * 32) = make_float2(a0, a1);
    short h0 = f2bf(a0), h1 = f2bf(a1);
    short l0 = f2bf(a0 - bf2f(h0)), l1 = f2bf(a1 - bf2f(h1));
    *(short2*)&Ah[buf][t * 2] = make_short2(h0, h1);
    *(short2*)&Al[buf][t * 2] = make_short2(l0, l1);
    __syncthreads();
    bf16x8 ah = *(const bf16x8*)&Ah[buf][lane * 8];
    bf16x8 al = *(const bf16x8*)&Al[buf][lane * 8];
    acc[0] = __builtin_amdgcn_mfma_f32_16x16x32_bf16(ah, b0h, acc[0], 0, 0, 0);
    acc[0] = __builtin_amdgcn_mfma_f32_16x16x32_bf16(al, b0h, acc[0], 0, 0, 0);
    acc[0] = __builtin_amdgcn_mfma_f32_16x16x32_bf16(ah, b0l, acc[0], 0, 0, 0);
    acc[1] = __builtin_amdgcn_mfma_f32_16x16x32_bf16(ah, b1h, acc[1], 0, 0, 0);
    acc[1] = __builtin_amdgcn_mfma_f32_16x16x32_bf16(al, b1h, acc[1], 0, 0, 0);
    acc[1] = __builtin_amdgcn_mfma_f32_16x16x32_bf16(ah, b1l, acc[1], 0, 0, 0);
    x = xn;
  }
#pragma unroll
  for (int c = 0; c < 2; ++c)
#pragma unroll
    for (int reg = 0; reg < 4; ++reg) {
      int mm = m0 + lq * 4 + reg;
      int n = nh * 128 + (w * 2 + c) * 16 + lm;
      C[mm * 512 + n] = acc[c][reg];
    }
}

// ---- per-iteration mid chain (round-13 config: 128 blocks, 64-h chunks) ----
__global__ __launch_bounds__(512) void k_mid(int first,
                                             const float* __restrict__ smat,
                                             const float* __restrict__ r_slot,
                                             const float* __restrict__ c_inte,
                                             const float* __restrict__ c_slot,
                                             const float* __restrict__ wsf_t,
                                             const float* __restrict__ vsf_t,
                                             float* __restrict__ f) {
  __shared__ float av[64];
  __shared__ float riv[512];
  __shared__ float red[512];
  __shared__ float tm[64], ts[64];
  const int b = blockIdx.x >> 3, hc = blockIdx.x & 7;
  const int t = threadIdx.x;
  const int hl = t & 63, kq = t >> 6;

  if (first) {
    riv[t] = c_inte[b * 512 + t];
  } else {
    if (t < 256) {
      int w = t >> 6, lane = t & 63;
      for (int r = w * 16; r < w * 16 + 16; ++r) {
        float v = smat[r * 64 + lane];
        float s = v;
        s += __shfl_xor(s, 1);
        s += __shfl_xor(s, 2);
        s += __shfl_xor(s, 4);
        s += __shfl_xor(s, 8);
        s += __shfl_xor(s, 16);
        s += __shfl_xor(s, 32);
        float d = __shfl(v, r);
        if (lane == 0) av[r] = d / s;
      }
    }
    __syncthreads();
    float a = 0.f;
    const float* rp = r_slot + b * 64 * 512 + t;
#pragma unroll 8
    for (int i = 0; i < 64; ++i) a += av[i] * rp[i * 512];
    riv[t] = a + c_inte[b * 512 + t];
  }
  __syncthreads();
  {
    const float* wp = wsf_t + hc * 64 + hl;
    float p = 0.f;
#pragma unroll 8
    for (int k = kq * 64; k < kq * 64 + 64; ++k) p += riv[k] * wp[k * 512];
    red[t] = p;
  }
  __syncthreads();
  if (t < 64) {
    float s = 0.f;
#pragma unroll
    for (int q = 0; q < 8; ++q) s += red[q * 64 + t];
    tm[t] = s;
  }
  __syncthreads();
  {
    float tmph = tm[hl];
    const float* cp = c_slot + (b * 64 + kq * 8) * 512 + hc * 64 + hl;
    float s = 0.f;
#pragma unroll
    for (int l = 0; l < 8; ++l) s += ftanh(cp[l * 512] + tmph);
    red[t] = s;
  }
  __syncthreads();
  if (t < 64) {
    float s = 0.f;
#pragma unroll
    for (int q = 0; q < 8; ++q) s += red[q * 64 + t];
    ts[t] = s;
  }
  __syncthreads();
  {
    const float* vp = vsf_t + (hc * 64) * 512 + t;
    float p = 0.f;
#pragma unroll 8
    for (int k = 0; k < 64; ++k) p += ts[k] * vp[k * 512];
    atomicAdd(&f[b * 512 + t], p);
  }
}

// ---- dominant kernel v9: TWO i-rows per block, 1024 threads (16 waves).
// Each wave owns one (i-row x 64g) sub-tile -> acc stays 64 regs (no spill);
// B fragments serve both rows -> B L2 traffic halves (512->256 MB/dispatch).
// LDS: 2 x 64 KB A + 4 KB red = 132 KB, 1 block/CU, 4 waves/SIMD.
__global__ __launch_bounds__(1024) void k_score(const float* __restrict__ hid,
                                                const float* __restrict__ sf,
                                                const short* __restrict__ wbp,
                                                float* __restrict__ smat,
                                                float* __restrict__ fz,
                                                float* __restrict__ oz) {
  __shared__ short As[2][16][2048];  // 128 KB: [i-row][ks][frag]
  __shared__ float red[16][64];      // 4 KB
  const int ip = blockIdx.x, b = blockIdx.y;  // ip: 0..31 (pair of i)
  const int t = threadIdx.x;                  // 0..1023
  if (fz && ip == 0 && t < 512) fz[b * 512 + t] = 0.f;
  if (oz && ip == 1 && b < 2 && t < 512) oz[b * 512 + t] = 0.f;
  const int w = t >> 6, lane = t & 63;
  const int lq = lane >> 4, lm = lane & 15;
  const int irow = w >> 3;  // wave's i-row (0/1)
  const int i0 = ip * 2;

  f32x4 acc[4][4];
#pragma unroll
  for (int r = 0; r < 4; ++r)
#pragma unroll
    for (int c = 0; c < 4; ++c) acc[r][c] = (f32x4){0.f, 0.f, 0.f, 0.f};

  // staging: threads 0..511 stage row 0, 512..1023 stage row 1
  const int srow = t >> 9;
  const int tt = t & 511;
  const int fid = tt >> 1, half = tt & 1;
  const int am = (fid >> 6) * 16 + (fid & 15);
  const int ak = ((fid >> 4) & 3) * 8 + half * 4;
  const int aoff = fid * 8 + half * 4;

  const float* hp0 = hid + (b * 64 + i0 + srow) * 512 + ak;
  const float* sp0 = sf + (b * 64 + am) * 512 + ak;

  // hoisted: first kstep's B fragments in flight during staging
  const bf16x8* gb = (const bf16x8*)wbp + ((w & 7) * 4) * 64 + lane;
  bf16x8 nb0 = gb[0];
  bf16x8 nb1 = gb[64];
  bf16x8 nb2 = gb[128];
  bf16x8 nb3 = gb[192];

#pragma unroll 4
  for (int ks = 0; ks < 16; ++ks) {
    float4 hv = *(const float4*)(hp0 + ks * 32);
    float4 sv = *(const float4*)(sp0 + ks * 32);
    uint2 pk;
    pk.x = pack2(ftanh(hv.x + sv.x), ftanh(hv.y + sv.y));
    pk.y = pack2(ftanh(hv.z + sv.z), ftanh(hv.w + sv.w));
    *(uint2*)&As[srow][ks][aoff] = pk;
  }
  __syncthreads();

  for (int ks = 0; ks < 16; ++ks) {
    bf16x8 b0 = nb0, b1 = nb1, b2 = nb2, b3 = nb3;
    if (ks < 15) {
      nb0 = gb[(ks + 1) * 2048];
      nb1 = gb[(ks + 1) * 2048 + 64];
      nb2 = gb[(ks + 1) * 2048 + 128];
      nb3 = gb[(ks + 1) * 2048 + 192];
    }
    bf16x8 af0 = *(const bf16x8*)&As[irow][ks][(0 * 64 + lane) * 8];
    bf16x8 af1 = *(const bf16x8*)&As[irow][ks][(1 * 64 + lane) * 8];
    bf16x8 af2 = *(const bf16x8*)&As[irow][ks][(2 * 64 + lane) * 8];
    bf16x8 af3 = *(const bf16x8*)&As[irow][ks][(3 * 64 + lane) * 8];
    acc[0][0] = __builtin_amdgcn_mfma_f32_16x16x32_bf16(af0, b0, acc[0][0], 0, 0, 0);
    acc[1][0] = __builtin_amdgcn_mfma_f32_16x16x32_bf16(af1, b0, acc[1][0], 0, 0, 0);
    acc[2][0] = __builtin_amdgcn_mfma_f32_16x16x32_bf16(af2, b0, acc[2][0], 0, 0, 0);
    acc[3][0] = __builtin_amdgcn_mfma_f32_16x16x32_bf16(af3, b0, acc[3][0], 0, 0, 0);
    acc[0][1] = __builtin_amdgcn_mfma_f32_16x16x32_bf16(af0, b1, acc[0][1], 0, 0, 0);
    acc[1][1] = __builtin_amdgcn_mfma_f32_16x16x32_bf16(af1, b1, acc[1][1], 0, 0, 0);
    acc[2][1] = __builtin_amdgcn_mfma_f32_16x16x32_bf16(af2, b1, acc[2][1], 0, 0, 0);
    acc[3][1] = __builtin_amdgcn_mfma_f32_16x16x32_bf16(af3, b1, acc[3][1], 0, 0, 0);
    acc[0][2] = __builtin_amdgcn_mfma_f32_16x16x32_bf16(af0, b2, acc[0][2], 0, 0, 0);
    acc[1][2] = __builtin_amdgcn_mfma_f32_16x16x32_bf16(af1, b2, acc[1][2], 0, 0, 0);
    acc[2][2] = __builtin_amdgcn_mfma_f32_16x16x32_bf16(af2, b2, acc[2][2], 0, 0, 0);
    acc[3][2] = __builtin_amdgcn_mfma_f32_16x16x32_bf16(af3, b2, acc[3][2], 0, 0, 0);
    acc[0][3] = __builtin_amdgcn_mfma_f32_16x16x32_bf16(af0, b3, acc[0][3], 0, 0, 0);
    acc[1][3] = __builtin_amdgcn_mfma_f32_16x16x32_bf16(af1, b3, acc[1][3], 0, 0, 0);
    acc[2][3] = __builtin_amdgcn_mfma_f32_16x16x32_bf16(af2, b3, acc[2][3], 0, 0, 0);
    acc[3][3] = __builtin_amdgcn_mfma_f32_16x16x32_bf16(af3, b3, acc[3][3], 0, 0, 0);
  }

  // exp + reduce over g. C/D: col=lm, row=lq*4+reg within each 16x16 tile.
#pragma unroll
  for (int r = 0; r < 4; ++r) {
#pragma unroll
    for (int reg = 0; reg < 4; ++reg) {
      float v = __expf(acc[r][0][reg]) + __expf(acc[r][1][reg]) +
                __expf(acc[r][2][reg]) + __expf(acc[r][3][reg]);
      v += __shfl_down(v, 8, 16);
      v += __shfl_down(v, 4, 16);
      v += __shfl_down(v, 2, 16);
      v += __shfl_down(v, 1, 16);
      if (lm == 0) red[w][r * 16 + lq * 4 + reg] = v;
    }
  }
  __syncthreads();
  if (t < 128) {
    const int il = t >> 6, j = t & 63;
    float s = 0.f;
#pragma unroll
    for (int ww = 0; ww < 8; ++ww) s += red[il * 8 + ww][j];
    atomicAdd(&smat[(i0 + il) * 64 + j], s);
  }
}

// ---- post (round-13 config): k_slot (bx<256) + k_fin (bx>=256) merged ----
__global__ __launch_bounds__(256) void k_post(const float* __restrict__ smat,
                                              const float* __restrict__ r_slot,
                                              const float* __restrict__ c_inte,
                                              const float* __restrict__ h,
                                              const float* __restrict__ wia_t,
                                              const float* __restrict__ wsa_t,
                                              float* __restrict__ out) {
  __shared__ float av[64], riv[64], red[256];
  const int t = threadIdx.x;
  if (blockIdx.x < 256) {
    int idx = blockIdx.x * 256 + t;  // 65536
    int ml = idx >> 6, n = idx & 63;
    const float* x1 = h + ml * 512;
    const float* x2 = r_slot + ml * 512;
    float acc = 0.f;
    for (int k = 0; k < 512; k += 4) {
      float4 x = *(const float4*)(x1 + k);
      acc += x.x * wsa_t[k * 64 + n] + x.y * wsa_t[(k + 1) * 64 + n] +
             x.z * wsa_t[(k + 2) * 64 + n] + x.w * wsa_t[(k + 3) * 64 + n];
    }
    for (int k = 0; k < 512; k += 4) {
      float4 x = *(const float4*)(x2 + k);
      acc += x.x * wsa_t[(512 + k) * 64 + n] + x.y * wsa_t[(513 + k) * 64 + n] +
             x.z * wsa_t[(514 + k) * 64 + n] + x.w * wsa_t[(515 + k) * 64 + n];
    }
    out[1024 + idx] = acc;
  } else {
    const int bb = blockIdx.x - 256;
    const int b = bb >> 3, kc = bb & 7;
    const int w = t >> 6, lane = t & 63;
    for (int r = w * 16; r < w * 16 + 16; ++r) {
      float v = smat[r * 64 + lane];
      float s = v;
      s += __shfl_xor(s, 1);
      s += __shfl_xor(s, 2);
      s += __shfl_xor(s, 4);
      s += __shfl_xor(s, 8);
      s += __shfl_xor(s, 16);
      s += __shfl_xor(s, 32);
      float d = __shfl(v, r);
      if (lane == 0) av[r] = d / s;
    }
    __syncthreads();
    {
      const int hh = kc * 64 + lane;
      float a = 0.f;
      const float* rp = r_slot + (b * 64 + w * 16) * 512 + hh;
#pragma unroll
      for (int i = 0; i < 16; ++i) a += av[w * 16 + i] * rp[i * 512];
      red[t] = a;
    }
    __syncthreads();
    if (t < 64)
      riv[t] = red[t] + red[t + 64] + red[t + 128] + red[t + 192] +
               c_inte[b * 512 + kc * 64 + t];
    __syncthreads();
    {
      const int n = lane;
      const float* hrow = h + (b * 64 + 63) * 512 + kc * 64;
      float p = 0.f;
#pragma unroll
      for (int k = w * 16; k < w * 16 + 16; ++k) {
        p += riv[k] * wia_t[(kc * 64 + k) * 64 + n];
        p += hrow[k] * wia_t[(512 + kc * 64 + k) * 64 + n];
      }
      red[t] = p;
    }
    __syncthreads();
    if (t < 64)
      atomicAdd(&out[b * 64 + t],
                red[t] + red[t + 64] + red[t + 128] + red[t + 192]);
  }
}

extern "C" void kernel_launch(void* const* d_in, const int* in_sizes, int n_in,
                              void* d_out, int out_size, void* d_ws, size_t ws_size,
                              hipStream_t stream) {
  const float* h      = (const float*)d_in[0];
  const float* c_slot = (const float*)d_in[1];
  const float* c_inte = (const float*)d_in[2];
  const float* W_SF   = (const float*)d_in[3];
  const float* V_SF   = (const float*)d_in[4];
  const float* V1_ID  = (const float*)d_in[5];
  const float* V2_w   = (const float*)d_in[6];
  const float* V2_b   = (const float*)d_in[7];
  const float* W_ID   = (const float*)d_in[8];
  const float* W_ia   = (const float*)d_in[9];
  const float* W_sa   = (const float*)d_in[10];
  float* out = (float*)d_out;

  float* ws     = (float*)d_ws;
  short* wbp    = (short*)ws;
  short* v1h    = (short*)(ws + 393216);
  short* v1l    = (short*)(ws + 524288);
  float* sfbuf  = ws + 655360;
  float* r_slot = ws + 1179648;
  float* hid    = ws + 1703936;
  float* smat   = ws + 2228224;
  float* f      = ws + 2232320;
  float* wia_t  = ws + 2240512;
  float* wsa_t  = ws + 2306048;
  float* wsf_t  = ws + 2371584;
  float* vsf_t  = ws + 2633728;

  k_lin1<<<dim3(64, 15), 256, 0, stream>>>(h, V2_w, V2_b, sfbuf,
                                           W_ID, V1_ID, W_ia, W_sa, W_SF, V_SF,
                                           wbp, v1h, v1l,
                                           wia_t, wsa_t, wsf_t, vsf_t, f);

  for (int it = 0; it < 3; ++it) {
    k_mid<<<128, 512, 0, stream>>>(it == 0 ? 1 : 0, smat, r_slot, c_inte,
                                   c_slot, wsf_t, vsf_t, f);
    k_lin<<<dim3(64, 4), 256, 0, stream>>>(c_slot, f, v1h, v1l,
                                           hid, r_slot, smat);
    k_score<<<dim3(32, 16), 1024, 0, stream>>>(hid, sfbuf, wbp, smat, f,
                                               it == 2 ? out : nullptr);
  }

  k_post<<<384, 256, 0, stream>>>(smat, r_slot, c_inte, h, wia_t, wsa_t, out);
}

// Round 16
// 301.334 us; speedup vs baseline: 1.0317x; 1.0317x over previous
//
#include <hip/hip_runtime.h>
#include <math.h>

// B=16, L=64, H=512, N_LABELS=64, ITERS=3
// Round-13 configuration (best measured: 301.6 us) — final.
//
// ws layout (float offsets):
//   wbp 0 [131072] W_ID bf16 B-fragment-major
//   v1h 393216, v1l 524288 [131072 each] split-bf16 V1
//   sfbuf 655360, r_slot 1179648, hid 1703936 [524288 each]
//   smat 2228224 [4096], f 2232320 [8192]
//   wia_t 2240512, wsa_t 2306048 [65536 each]
//   wsf_t 2371584, vsf_t 2633728 [262144 each]

typedef __attribute__((ext_vector_type(8))) short bf16x8;
typedef __attribute__((ext_vector_type(4))) float f32x4;

__device__ inline short f2bf(float x) {  // RNE
  unsigned u = __float_as_uint(x);
  unsigned r = (u + 0x7fffu + ((u >> 16) & 1u)) >> 16;
  return (short)r;
}
__device__ inline float bf2f(short s) {
  return __uint_as_float(((unsigned)(unsigned short)s) << 16);
}
__device__ inline unsigned pack2(float a, float b) {  // truncating 2xbf16
  return (__float_as_uint(a) >> 16) | (__float_as_uint(b) & 0xffff0000u);
}
__device__ inline float ftanh(float x) {
  float t = __expf(2.f * x);
  return 1.f - 2.f * __builtin_amdgcn_rcpf(t + 1.f);
}
__device__ inline void split8(float4 a, float4 b, bf16x8* hi, bf16x8* lo) {
  float xs[8] = {a.x, a.y, a.z, a.w, b.x, b.y, b.z, b.w};
  bf16x8 h, l;
#pragma unroll
  for (int e = 0; e < 8; ++e) {
    short hh = f2bf(xs[e]);
    h[e] = hh;
    l[e] = f2bf(xs[e] - bf2f(hh));
  }
  *hi = h;
  *lo = l;
}

// ---- first linear (raw f32 B, split in-register) + all prep as extra planes.
__global__ __launch_bounds__(256) void k_lin1(
    const float* __restrict__ A, const float* __restrict__ rawB,
    const float* __restrict__ bias, float* __restrict__ C,
    const float* __restrict__ W_ID, const float* __restrict__ V1,
    const float* __restrict__ W_ia, const float* __restrict__ W_sa,
    const float* __restrict__ W_SF, const float* __restrict__ V_SF,
    short* __restrict__ wbp, short* __restrict__ v1h, short* __restrict__ v1l,
    float* __restrict__ wia_t, float* __restrict__ wsa_t,
    float* __restrict__ wsf_t, float* __restrict__ vsf_t,
    float* __restrict__ fzero) {
  __shared__ short Ah[2][512], Al[2][512];
  __shared__ float tile[64][65];
  const int nh = blockIdx.y;
  const int t = threadIdx.x;

  if (nh >= 4) {
    const int pid = (nh - 4) * 64 + blockIdx.x;
    if (pid < 256) {  // wbp pack
#pragma unroll
      for (int e = 0; e < 4; ++e) {
        int idx = pid * 1024 + e * 256 + t;
        int j = idx & 7, lane = (idx >> 3) & 63;
        int ntile = (idx >> 9) & 31, kstep = idx >> 14;
        int g = ntile * 16 + (lane & 15);
        int h = kstep * 32 + (lane >> 4) * 8 + j;
        wbp[idx] = f2bf(W_ID[g * 512 + h]);
      }
    } else if (pid < 512) {  // v1 split pack
      int p = pid - 256;
#pragma unroll
      for (int e = 0; e < 4; ++e) {
        int idx = p * 1024 + e * 256 + t;
        int j = idx & 7, lane = (idx >> 3) & 63;
        int ntile = (idx >> 9) & 31, kstep = idx >> 14;
        int g = ntile * 16 + (lane & 15);
        int h = kstep * 32 + (lane >> 4) * 8 + j;
        float x = V1[g * 512 + h];
        short hi = f2bf(x);
        v1h[idx] = hi;
        v1l[idx] = f2bf(x - bf2f(hi));
      }
    } else if (pid < 672) {  // transposes
      int p = pid - 512;
      const float* tin;
      float* tout;
      int R, C2, c0, r0;
      if (p < 64) {
        tin = W_SF; tout = wsf_t; R = 512; C2 = 512;
        c0 = (p & 7) * 64; r0 = (p >> 3) * 64;
      } else if (p < 128) {
        int q = p - 64;
        tin = V_SF; tout = vsf_t; R = 512; C2 = 512;
        c0 = (q & 7) * 64; r0 = (q >> 3) * 64;
      } else if (p < 144) {
        tin = W_ia; tout = wia_t; R = 64; C2 = 1024;
        c0 = (p - 128) * 64; r0 = 0;
      } else {
        tin = W_sa; tout = wsa_t; R = 64; C2 = 1024;
        c0 = (p - 144) * 64; r0 = 0;
      }
      const int tx = t & 63, ty = t >> 6;
#pragma unroll
      for (int it2 = 0; it2 < 16; ++it2) {
        int rl = ty + it2 * 4;
        tile[rl][tx] = tin[(r0 + rl) * C2 + c0 + tx];
      }
      __syncthreads();
#pragma unroll
      for (int it2 = 0; it2 < 16; ++it2) {
        int cl = ty + it2 * 4;
        tout[(c0 + cl) * R + r0 + tx] = tile[tx][cl];
      }
    }
    return;
  }

  // ---- gemm planes (nh<4): raw f32 B, split in-register ----
  const int m0 = blockIdx.x * 16;
  if (fzero && nh == 1 && blockIdx.x < 16) {
    fzero[blockIdx.x * 512 + t] = 0.f;
    fzero[blockIdx.x * 512 + 256 + t] = 0.f;
  }
  const int w = t >> 6, lane = t & 63;
  const int lq = lane >> 4, lm = lane & 15;
  f32x4 acc[2];
#pragma unroll
  for (int c = 0; c < 2; ++c) acc[c] = (f32x4){0.f, 0.f, 0.f, 0.f};

  const int nt0 = nh * 8 + w * 2;
  const float* vb0 = rawB + (nt0 * 16 + lm) * 512 + lq * 8;
  const float* vb1 = vb0 + 16 * 512;

  const int la = t >> 2, j0 = (t & 3) * 2;
  const int m = la & 15, kk = (la >> 4) * 8 + j0;
  const float* abase = A + (m0 + m) * 512 + kk;
  float2 x = *(const float2*)abase;

  for (int ks = 0; ks < 16; ++ks) {
    const int buf = ks & 1;
    float4 q0 = *(const float4*)(vb0 + ks * 32);
    float4 q1 = *(const float4*)(vb0 + ks * 32 + 4);
    float4 p0 = *(const float4*)(vb1 + ks * 32);
    float4 p1 = *(const float4*)(vb1 + ks * 32 + 4);
    float2 xn = x;
    if (ks < 15) xn = *(const float2*)(abase + (ks + 1) * 32);
    short h0 = f2bf(x.x), h1 = f2bf(x.y);
    short l0 = f2bf(x.x - bf2f(h0)), l1 = f2bf(x.y - bf2f(h1));
    *(short2*)&Ah[buf][t * 2] = make_short2(h0, h1);
    *(short2*)&Al[buf][t * 2] = make_short2(l0, l1);
    bf16x8 b0h, b0l, b1h, b1l;
    split8(q0, q1, &b0h, &b0l);
    split8(p0, p1, &b1h, &b1l);
    __syncthreads();
    bf16x8 ah = *(const bf16x8*)&Ah[buf][lane * 8];
    bf16x8 al = *(const bf16x8*)&Al[buf][lane * 8];
    acc[0] = __builtin_amdgcn_mfma_f32_16x16x32_bf16(ah, b0h, acc[0], 0, 0, 0);
    acc[0] = __builtin_amdgcn_mfma_f32_16x16x32_bf16(al, b0h, acc[0], 0, 0, 0);
    acc[0] = __builtin_amdgcn_mfma_f32_16x16x32_bf16(ah, b0l, acc[0], 0, 0, 0);
    acc[1] = __builtin_amdgcn_mfma_f32_16x16x32_bf16(ah, b1h, acc[1], 0, 0, 0);
    acc[1] = __builtin_amdgcn_mfma_f32_16x16x32_bf16(al, b1h, acc[1], 0, 0, 0);
    acc[1] = __builtin_amdgcn_mfma_f32_16x16x32_bf16(ah, b1l, acc[1], 0, 0, 0);
    x = xn;
  }
#pragma unroll
  for (int c = 0; c < 2; ++c)
#pragma unroll
    for (int reg = 0; reg < 4; ++reg) {
      int mm = m0 + lq * 4 + reg;
      int n = (nt0 + c) * 16 + lm;
      C[mm * 512 + n] = acc[c][reg] + bias[n];
    }
}

// ---- split-precision MFMA linear (loop version, packed B) ----
// grid (64, 4); A = f[b,:] (x) c_slot, nh==0 writes r_slot, zeroes smat.
__global__ __launch_bounds__(256) void k_lin(const float* __restrict__ c_slot,
                                             const float* __restrict__ f,
                                             const short* __restrict__ bh,
                                             const short* __restrict__ bl,
                                             float* __restrict__ C,
                                             float* __restrict__ rs_out,
                                             float* __restrict__ smat0) {
  __shared__ short Ah[2][512], Al[2][512];
  __shared__ float fl[512];
  const int m0 = blockIdx.x * 16;
  const int nh = blockIdx.y;
  const int t = threadIdx.x;
  if (nh == 0 && blockIdx.x < 8) {
    smat0[blockIdx.x * 512 + t] = 0.f;
    smat0[blockIdx.x * 512 + 256 + t] = 0.f;
  }
  fl[t] = f[(blockIdx.x >> 2) * 512 + t];
  fl[t + 256] = f[(blockIdx.x >> 2) * 512 + 256 + t];
  const int w = t >> 6, lane = t & 63;
  const int lq = lane >> 4, lm = lane & 15;
  f32x4 acc[2];
#pragma unroll
  for (int c = 0; c < 2; ++c) acc[c] = (f32x4){0.f, 0.f, 0.f, 0.f};

  const bf16x8* gbh = (const bf16x8*)bh + (nh * 8 + w * 2) * 64 + lane;
  const bf16x8* gbl = (const bf16x8*)bl + (nh * 8 + w * 2) * 64 + lane;

  const int la = t >> 2, j0 = (t & 3) * 2;
  const int m = la & 15, kk = (la >> 4) * 8 + j0;
  const float* abase = c_slot + (m0 + m) * 512 + kk;
  float* rbase = rs_out + (m0 + m) * 512 + kk;
  __syncthreads();  // fl ready
  float2 x = *(const float2*)abase;

  for (int ks = 0; ks < 16; ++ks) {
    const int buf = ks & 1;
    bf16x8 b0h = gbh[ks * 2048];
    bf16x8 b1h = gbh[ks * 2048 + 64];
    bf16x8 b0l = gbl[ks * 2048];
    bf16x8 b1l = gbl[ks * 2048 + 64];
    float2 xn = x;
    if (ks < 15) xn = *(const float2*)(abase + (ks + 1) * 32);
    float a0 = x.x * fl[ks * 32 + kk];
    float a1 = x.y * fl[ks * 32 + kk + 1];
    if (nh == 0) *(float2*)(rbase + ks * 32) = make_float2(a0, a1);
    short h0 = f2bf(a0), h1 = f2bf(a1);
    short l0 = f2bf(a0 - bf2f(h0)), l1 = f2bf(a1 - bf2f(h1));
    *(short2*)&Ah[buf][t * 2] = make_short2(h0, h1);
    *(short2*)&Al[buf][t * 2] = make_short2(l0, l1);
    __syncthreads();
    bf16x8 ah = *(const bf16x8*)&Ah[buf][lane * 8];
    bf16x8 al = *(const bf16x8*)&Al[buf][lane * 8];
    acc[0] = __builtin_amdgcn_mfma_f32_16x16x32_bf16(ah, b0h, acc[0], 0, 0, 0);
    acc[0] = __builtin_amdgcn_mfma_f32_16x16x32_bf16(al, b0h, acc[0], 0, 0, 0);
    acc[0] = __builtin_amdgcn_mfma_f32_16x16x32_bf16(ah, b0l, acc[0], 0, 0, 0);
    acc[1] = __builtin_amdgcn_mfma_f32_16x16x32_bf16(ah, b1h, acc[1], 0, 0, 0);
    acc[1] = __builtin_amdgcn_mfma_f32_16x16x32_bf16(al, b1h, acc[1], 0, 0, 0);
    acc[1] = __builtin_amdgcn_mfma_f32_16x16x32_bf16(ah, b1l, acc[1], 0, 0, 0);
    x = xn;
  }
#pragma unroll
  for (int c = 0; c < 2; ++c)
#pragma unroll
    for (int reg = 0; reg < 4; ++reg) {
      int mm = m0 + lq * 4 + reg;
      int n = nh * 128 + (w * 2 + c) * 16 + lm;
      C[mm * 512 + n] = acc[c][reg];
    }
}

// ---- per-iteration mid chain: 128 blocks, 64-h chunks, coalesced ----
__global__ __launch_bounds__(512) void k_mid(int first,
                                             const float* __restrict__ smat,
                                             const float* __restrict__ r_slot,
                                             const float* __restrict__ c_inte,
                                             const float* __restrict__ c_slot,
                                             const float* __restrict__ wsf_t,
                                             const float* __restrict__ vsf_t,
                                             float* __restrict__ f) {
  __shared__ float av[64];
  __shared__ float riv[512];
  __shared__ float red[512];
  __shared__ float tm[64], ts[64];
  const int b = blockIdx.x >> 3, hc = blockIdx.x & 7;
  const int t = threadIdx.x;
  const int hl = t & 63, kq = t >> 6;

  if (first) {
    riv[t] = c_inte[b * 512 + t];
  } else {
    if (t < 256) {
      int w = t >> 6, lane = t & 63;
      for (int r = w * 16; r < w * 16 + 16; ++r) {
        float v = smat[r * 64 + lane];
        float s = v;
        s += __shfl_xor(s, 1);
        s += __shfl_xor(s, 2);
        s += __shfl_xor(s, 4);
        s += __shfl_xor(s, 8);
        s += __shfl_xor(s, 16);
        s += __shfl_xor(s, 32);
        float d = __shfl(v, r);
        if (lane == 0) av[r] = d / s;
      }
    }
    __syncthreads();
    float a = 0.f;
    const float* rp = r_slot + b * 64 * 512 + t;
#pragma unroll 8
    for (int i = 0; i < 64; ++i) a += av[i] * rp[i * 512];
    riv[t] = a + c_inte[b * 512 + t];
  }
  __syncthreads();
  {
    const float* wp = wsf_t + hc * 64 + hl;
    float p = 0.f;
#pragma unroll 8
    for (int k = kq * 64; k < kq * 64 + 64; ++k) p += riv[k] * wp[k * 512];
    red[t] = p;
  }
  __syncthreads();
  if (t < 64) {
    float s = 0.f;
#pragma unroll
    for (int q = 0; q < 8; ++q) s += red[q * 64 + t];
    tm[t] = s;
  }
  __syncthreads();
  {
    float tmph = tm[hl];
    const float* cp = c_slot + (b * 64 + kq * 8) * 512 + hc * 64 + hl;
    float s = 0.f;
#pragma unroll
    for (int l = 0; l < 8; ++l) s += ftanh(cp[l * 512] + tmph);
    red[t] = s;
  }
  __syncthreads();
  if (t < 64) {
    float s = 0.f;
#pragma unroll
    for (int q = 0; q < 8; ++q) s += red[q * 64 + t];
    ts[t] = s;
  }
  __syncthreads();
  {
    const float* vp = vsf_t + (hc * 64) * 512 + t;
    float p = 0.f;
#pragma unroll 8
    for (int k = 0; k < 64; ++k) p += ts[k] * vp[k * 512];
    atomicAdd(&f[b * 512 + t], p);
  }
}

// ---- dominant kernel v8: whole A staged once, 1 barrier, B prefetch ----
__global__ __launch_bounds__(512, 4) void k_score(const float* __restrict__ hid,
                                                  const float* __restrict__ sf,
                                                  const short* __restrict__ wbp,
                                                  float* __restrict__ smat,
                                                  float* __restrict__ fz,
                                                  float* __restrict__ oz) {
  __shared__ short As[16][2048];  // 64 KB
  __shared__ float red[8][64];
  const int i = blockIdx.x, b = blockIdx.y;
  const int t = threadIdx.x;
  if (fz && i == 0) fz[b * 512 + t] = 0.f;
  if (oz && i == 1 && b < 2) oz[b * 512 + t] = 0.f;
  const int w = t >> 6, lane = t & 63;
  const int lq = lane >> 4, lm = lane & 15;

  f32x4 acc[4][4];
#pragma unroll
  for (int r = 0; r < 4; ++r)
#pragma unroll
    for (int c = 0; c < 4; ++c) acc[r][c] = (f32x4){0.f, 0.f, 0.f, 0.f};

  const float* hrow = hid + (b * 64 + i) * 512;
  const float* sfb = sf + b * 64 * 512;

  const int fid = t >> 1, half = t & 1;
  const int am = (fid >> 6) * 16 + (fid & 15);
  const int ak = ((fid >> 4) & 3) * 8 + half * 4;
  const int aoff = fid * 8 + half * 4;

  const float* hp0 = hrow + ak;
  const float* sp0 = sfb + am * 512 + ak;

  const bf16x8* gb = (const bf16x8*)wbp + (w * 4) * 64 + lane;
  bf16x8 nb0 = gb[0];
  bf16x8 nb1 = gb[64];
  bf16x8 nb2 = gb[128];
  bf16x8 nb3 = gb[192];

#pragma unroll 4
  for (int ks = 0; ks < 16; ++ks) {
    float4 hv = *(const float4*)(hp0 + ks * 32);
    float4 sv = *(const float4*)(sp0 + ks * 32);
    uint2 pk;
    pk.x = pack2(ftanh(hv.x + sv.x), ftanh(hv.y + sv.y));
    pk.y = pack2(ftanh(hv.z + sv.z), ftanh(hv.w + sv.w));
    *(uint2*)&As[ks][aoff] = pk;
  }
  __syncthreads();

  for (int ks = 0; ks < 16; ++ks) {
    bf16x8 b0 = nb0, b1 = nb1, b2 = nb2, b3 = nb3;
    if (ks < 15) {
      nb0 = gb[(ks + 1) * 2048];
      nb1 = gb[(ks + 1) * 2048 + 64];
      nb2 = gb[(ks + 1) * 2048 + 128];
      nb3 = gb[(ks + 1) * 2048 + 192];
    }
    bf16x8 af0 = *(const bf16x8*)&As[ks][(0 * 64 + lane) * 8];
    bf16x8 af1 = *(const bf16x8*)&As[ks][(1 * 64 + lane) * 8];
    bf16x8 af2 = *(const bf16x8*)&As[ks][(2 * 64 + lane) * 8];
    bf16x8 af3 = *(const bf16x8*)&As[ks][(3 * 64 + lane) * 8];
    acc[0][0] = __builtin_amdgcn_mfma_f32_16x16x32_bf16(af0, b0, acc[0][0], 0, 0, 0);
    acc[1][0] = __builtin_amdgcn_mfma_f32_16x16x32_bf16(af1, b0, acc[1][0], 0, 0, 0);
    acc[2][0] = __builtin_amdgcn_mfma_f32_16x16x32_bf16(af2, b0, acc[2][0], 0, 0, 0);
    acc[3][0] = __builtin_amdgcn_mfma_f32_16x16x32_bf16(af3, b0, acc[3][0], 0, 0, 0);
    acc[0][1] = __builtin_amdgcn_mfma_f32_16x16x32_bf16(af0, b1, acc[0][1], 0, 0, 0);
    acc[1][1] = __builtin_amdgcn_mfma_f32_16x16x32_bf16(af1, b1, acc[1][1], 0, 0, 0);
    acc[2][1] = __builtin_amdgcn_mfma_f32_16x16x32_bf16(af2, b1, acc[2][1], 0, 0, 0);
    acc[3][1] = __builtin_amdgcn_mfma_f32_16x16x32_bf16(af3, b1, acc[3][1], 0, 0, 0);
    acc[0][2] = __builtin_amdgcn_mfma_f32_16x16x32_bf16(af0, b2, acc[0][2], 0, 0, 0);
    acc[1][2] = __builtin_amdgcn_mfma_f32_16x16x32_bf16(af1, b2, acc[1][2], 0, 0, 0);
    acc[2][2] = __builtin_amdgcn_mfma_f32_16x16x32_bf16(af2, b2, acc[2][2], 0, 0, 0);
    acc[3][2] = __builtin_amdgcn_mfma_f32_16x16x32_bf16(af3, b2, acc[3][2], 0, 0, 0);
    acc[0][3] = __builtin_amdgcn_mfma_f32_16x16x32_bf16(af0, b3, acc[0][3], 0, 0, 0);
    acc[1][3] = __builtin_amdgcn_mfma_f32_16x16x32_bf16(af1, b3, acc[1][3], 0, 0, 0);
    acc[2][3] = __builtin_amdgcn_mfma_f32_16x16x32_bf16(af2, b3, acc[2][3], 0, 0, 0);
    acc[3][3] = __builtin_amdgcn_mfma_f32_16x16x32_bf16(af3, b3, acc[3][3], 0, 0, 0);
  }

#pragma unroll
  for (int r = 0; r < 4; ++r) {
#pragma unroll
    for (int reg = 0; reg < 4; ++reg) {
      float v = __expf(acc[r][0][reg]) + __expf(acc[r][1][reg]) +
                __expf(acc[r][2][reg]) + __expf(acc[r][3][reg]);
      v += __shfl_down(v, 8, 16);
      v += __shfl_down(v, 4, 16);
      v += __shfl_down(v, 2, 16);
      v += __shfl_down(v, 1, 16);
      if (lm == 0) red[w][r * 16 + lq * 4 + reg] = v;
    }
  }
  __syncthreads();
  if (t < 64) {
    float s = 0.f;
#pragma unroll
    for (int ww = 0; ww < 8; ++ww) s += red[ww][t];
    atomicAdd(&smat[i * 64 + t], s);
  }
}

// ---- post: k_slot (bx<256) + k_fin (bx>=256) merged ----
__global__ __launch_bounds__(256) void k_post(const float* __restrict__ smat,
                                              const float* __restrict__ r_slot,
                                              const float* __restrict__ c_inte,
                                              const float* __restrict__ h,
                                              const float* __restrict__ wia_t,
                                              const float* __restrict__ wsa_t,
                                              float* __restrict__ out) {
  __shared__ float av[64], riv[64], red[256];
  const int t = threadIdx.x;
  if (blockIdx.x < 256) {
    int idx = blockIdx.x * 256 + t;  // 65536
    int ml = idx >> 6, n = idx & 63;
    const float* x1 = h + ml * 512;
    const float* x2 = r_slot + ml * 512;
    float acc = 0.f;
    for (int k = 0; k < 512; k += 4) {
      float4 x = *(const float4*)(x1 + k);
      acc += x.x * wsa_t[k * 64 + n] + x.y * wsa_t[(k + 1) * 64 + n] +
             x.z * wsa_t[(k + 2) * 64 + n] + x.w * wsa_t[(k + 3) * 64 + n];
    }
    for (int k = 0; k < 512; k += 4) {
      float4 x = *(const float4*)(x2 + k);
      acc += x.x * wsa_t[(512 + k) * 64 + n] + x.y * wsa_t[(513 + k) * 64 + n] +
             x.z * wsa_t[(514 + k) * 64 + n] + x.w * wsa_t[(515 + k) * 64 + n];
    }
    out[1024 + idx] = acc;
  } else {
    const int bb = blockIdx.x - 256;
    const int b = bb >> 3, kc = bb & 7;
    const int w = t >> 6, lane = t & 63;
    for (int r = w * 16; r < w * 16 + 16; ++r) {
      float v = smat[r * 64 + lane];
      float s = v;
      s += __shfl_xor(s, 1);
      s += __shfl_xor(s, 2);
      s += __shfl_xor(s, 4);
      s += __shfl_xor(s, 8);
      s += __shfl_xor(s, 16);
      s += __shfl_xor(s, 32);
      float d = __shfl(v, r);
      if (lane == 0) av[r] = d / s;
    }
    __syncthreads();
    {
      const int hh = kc * 64 + lane;
      float a = 0.f;
      const float* rp = r_slot + (b * 64 + w * 16) * 512 + hh;
#pragma unroll
      for (int i = 0; i < 16; ++i) a += av[w * 16 + i] * rp[i * 512];
      red[t] = a;
    }
    __syncthreads();
    if (t < 64)
      riv[t] = red[t] + red[t + 64] + red[t + 128] + red[t + 192] +
               c_inte[b * 512 + kc * 64 + t];
    __syncthreads();
    {
      const int n = lane;
      const float* hrow = h + (b * 64 + 63) * 512 + kc * 64;
      float p = 0.f;
#pragma unroll
      for (int k = w * 16; k < w * 16 + 16; ++k) {
        p += riv[k] * wia_t[(kc * 64 + k) * 64 + n];
        p += hrow[k] * wia_t[(512 + kc * 64 + k) * 64 + n];
      }
      red[t] = p;
    }
    __syncthreads();
    if (t < 64)
      atomicAdd(&out[b * 64 + t],
                red[t] + red[t + 64] + red[t + 128] + red[t + 192]);
  }
}

extern "C" void kernel_launch(void* const* d_in, const int* in_sizes, int n_in,
                              void* d_out, int out_size, void* d_ws, size_t ws_size,
                              hipStream_t stream) {
  const float* h      = (const float*)d_in[0];
  const float* c_slot = (const float*)d_in[1];
  const float* c_inte = (const float*)d_in[2];
  const float* W_SF   = (const float*)d_in[3];
  const float* V_SF   = (const float*)d_in[4];
  const float* V1_ID  = (const float*)d_in[5];
  const float* V2_w   = (const float*)d_in[6];
  const float* V2_b   = (const float*)d_in[7];
  const float* W_ID   = (const float*)d_in[8];
  const float* W_ia   = (const float*)d_in[9];
  const float* W_sa   = (const float*)d_in[10];
  float* out = (float*)d_out;

  float* ws     = (float*)d_ws;
  short* wbp    = (short*)ws;
  short* v1h    = (short*)(ws + 393216);
  short* v1l    = (short*)(ws + 524288);
  float* sfbuf  = ws + 655360;
  float* r_slot = ws + 1179648;
  float* hid    = ws + 1703936;
  float* smat   = ws + 2228224;
  float* f      = ws + 2232320;
  float* wia_t  = ws + 2240512;
  float* wsa_t  = ws + 2306048;
  float* wsf_t  = ws + 2371584;
  float* vsf_t  = ws + 2633728;

  k_lin1<<<dim3(64, 15), 256, 0, stream>>>(h, V2_w, V2_b, sfbuf,
                                           W_ID, V1_ID, W_ia, W_sa, W_SF, V_SF,
                                           wbp, v1h, v1l,
                                           wia_t, wsa_t, wsf_t, vsf_t, f);

  for (int it = 0; it < 3; ++it) {
    k_mid<<<128, 512, 0, stream>>>(it == 0 ? 1 : 0, smat, r_slot, c_inte,
                                   c_slot, wsf_t, vsf_t, f);
    k_lin<<<dim3(64, 4), 256, 0, stream>>>(c_slot, f, v1h, v1l,
                                           hid, r_slot, smat);
    k_score<<<dim3(64, 16), 512, 0, stream>>>(hid, sfbuf, wbp, smat, f,
                                              it == 2 ? out : nullptr);
  }

  k_post<<<384, 256, 0, stream>>>(smat, r_slot, c_inte, h, wia_t, wsa_t, out);
}